// Round 12
// baseline (3106.515 us; speedup 1.0000x reference)
//
#include <hip/hip_runtime.h>

#define B_    256
#define S_    512
#define OBS_  64
#define ZD_   16
#define HID_  256
#define ITERS_ 4
#define RT_   64          // candidates (rows) per block (eight 8-row groups)
#define STRH_ 68          // LDS leading stride: 64 rows + 4 pad

// ---------------------------------------------------------------------------
// Encoder + per-batch-row layer-1 s0-part precompute (pre-activation)
// ---------------------------------------------------------------------------
__global__ __launch_bounds__(256) void enc_kernel(
    const float* __restrict__ s0,
    const float* __restrict__ w1, const float* __restrict__ b1,
    const float* __restrict__ w2, const float* __restrict__ b2,
    const float* __restrict__ zmw, const float* __restrict__ zmb,
    const float* __restrict__ zlw, const float* __restrict__ zlb,
    const float* __restrict__ mu_w1, const float* __restrict__ mu_b1,
    const float* __restrict__ risk_w1, const float* __restrict__ risk_b1,
    float* __restrict__ mu, float* __restrict__ stdv, float* __restrict__ bscore,
    float* __restrict__ base_mu, float* __restrict__ base_risk)
{
    __shared__ float s0s[OBS_];
    __shared__ float h1[HID_];
    __shared__ float h2[HID_];
    const int b = blockIdx.x, tid = threadIdx.x;
    if (tid < OBS_) s0s[tid] = s0[b * OBS_ + tid];
    __syncthreads();
    {
        float am = mu_b1[tid], ar = risk_b1[tid];
        for (int k = 0; k < OBS_; ++k) {
            am = fmaf(s0s[k], mu_w1[k * 256 + tid], am);
            ar = fmaf(s0s[k], risk_w1[k * 256 + tid], ar);
        }
        base_mu[b * 256 + tid]   = am;
        base_risk[b * 256 + tid] = ar;
    }
    float a = b1[tid];
    for (int k = 0; k < OBS_; ++k) a = fmaf(s0s[k], w1[k * HID_ + tid], a);
    h1[tid] = fmaxf(a, 0.f);
    __syncthreads();
    float a2 = b2[tid];
    for (int k = 0; k < HID_; ++k) a2 = fmaf(h1[k], w2[k * HID_ + tid], a2);
    h2[tid] = fmaxf(a2, 0.f);
    __syncthreads();
    if (tid < ZD_) {
        float m = zmb[tid];
        for (int k = 0; k < HID_; ++k) m = fmaf(h2[k], zmw[k * ZD_ + tid], m);
        mu[b * ZD_ + tid] = m;
    } else if (tid < 2 * ZD_) {
        const int d = tid - ZD_;
        float l = zlb[d];
        for (int k = 0; k < HID_; ++k) l = fmaf(h2[k], zlw[k * ZD_ + d], l);
        l = fminf(fmaxf(l, -4.f), 2.f);
        stdv[b * ZD_ + d] = expf(l);
    } else if (tid == 2 * ZD_) {
        bscore[b] = -INFINITY;
    }
}

// 8 rows x 8 cols of FMAs from one broadcast LDS row segment (2 b128 reads)
__device__ __forceinline__ void fma8x8(
    const float* __restrict__ row, const float4 w0, const float4 w1,
    float acc[8][8])
{
    const float4 q0 = *(const float4*)(row);
    const float4 q1 = *(const float4*)(row + 4);
    const float aa[8] = {q0.x,q0.y,q0.z,q0.w, q1.x,q1.y,q1.z,q1.w};
    const float ww[8] = {w0.x,w0.y,w0.z,w0.w, w1.x,w1.y,w1.z,w1.w};
#pragma unroll
    for (int c = 0; c < 8; ++c)
#pragma unroll
        for (int r = 0; r < 8; ++r)
            acc[c][r] = fmaf(aa[r], ww[c], acc[c][r]);
}

// 8 rows x 4 cols (sig l3)
__device__ __forceinline__ void fma8x4(
    const float* __restrict__ row, const float4 w0, float acc[4][8])
{
    const float4 q0 = *(const float4*)(row);
    const float4 q1 = *(const float4*)(row + 4);
    const float aa[8] = {q0.x,q0.y,q0.z,q0.w, q1.x,q1.y,q1.z,q1.w};
    const float ww[4] = {w0.x,w0.y,w0.z,w0.w};
#pragma unroll
    for (int c = 0; c < 4; ++c)
#pragma unroll
        for (int r = 0; r < 8; ++r)
            acc[c][r] = fmaf(aa[r], ww[c], acc[c][r]);
}

// 8-col GEMM over 8 rows; K multiple of 8; 4+4 weight prefetch (2 dwordx4/k).
__device__ __forceinline__ void gemm_k8(
    const float* __restrict__ inS, int K,
    const float* __restrict__ wcol, float acc[8][8])
{
    float4 wA[4][2], wB[4][2];
#pragma unroll
    for (int i = 0; i < 4; ++i) {
        wA[i][0] = *(const float4*)(wcol + (size_t)i * 256);
        wA[i][1] = *(const float4*)(wcol + (size_t)i * 256 + 4);
    }
#pragma unroll 1
    for (int k0 = 0; k0 < K; k0 += 8) {
#pragma unroll
        for (int i = 0; i < 4; ++i) {
            wB[i][0] = *(const float4*)(wcol + (size_t)(k0 + 4 + i) * 256);
            wB[i][1] = *(const float4*)(wcol + (size_t)(k0 + 4 + i) * 256 + 4);
        }
#pragma unroll
        for (int i = 0; i < 4; ++i)
            fma8x8(inS + (k0 + i) * STRH_, wA[i][0], wA[i][1], acc);
        if (k0 + 8 < K) {
#pragma unroll
            for (int i = 0; i < 4; ++i) {
                wA[i][0] = *(const float4*)(wcol + (size_t)(k0 + 8 + i) * 256);
                wA[i][1] = *(const float4*)(wcol + (size_t)(k0 + 8 + i) * 256 + 4);
            }
        }
#pragma unroll
        for (int i = 0; i < 4; ++i)
            fma8x8(inS + (k0 + 4 + i) * STRH_, wB[i][0], wB[i][1], acc);
    }
}

// 4-col GEMM over 8 rows (sig l3: stride 128, 1 dwordx4/k)
__device__ __forceinline__ void gemm_l3(
    const float* __restrict__ inS, int K,
    const float* __restrict__ wcol, float acc[4][8])
{
    float4 wA[4], wB[4];
#pragma unroll
    for (int i = 0; i < 4; ++i) wA[i] = *(const float4*)(wcol + (size_t)i * 128);
#pragma unroll 1
    for (int k0 = 0; k0 < K; k0 += 8) {
#pragma unroll
        for (int i = 0; i < 4; ++i)
            wB[i] = *(const float4*)(wcol + (size_t)(k0 + 4 + i) * 128);
#pragma unroll
        for (int i = 0; i < 4; ++i)
            fma8x4(inS + (k0 + i) * STRH_, wA[i], acc);
        if (k0 + 8 < K) {
#pragma unroll
            for (int i = 0; i < 4; ++i)
                wA[i] = *(const float4*)(wcol + (size_t)(k0 + 8 + i) * 128);
        }
#pragma unroll
        for (int i = 0; i < 4; ++i)
            fma8x4(inS + (k0 + 4 + i) * STRH_, wB[i], acc);
    }
}

// store 8 cols x 8 rows with relu
__device__ __forceinline__ void store8x8_relu(float* __restrict__ dst, int c0,
                                              int g8, const float acc[8][8])
{
#pragma unroll
    for (int c = 0; c < 8; ++c) {
#pragma unroll
        for (int q = 0; q < 2; ++q) {
            float4 o;
            o.x = fmaxf(acc[c][4*q+0], 0.f); o.y = fmaxf(acc[c][4*q+1], 0.f);
            o.z = fmaxf(acc[c][4*q+2], 0.f); o.w = fmaxf(acc[c][4*q+3], 0.f);
            *(float4*)(dst + (size_t)(c0 + c) * STRH_ + g8 + 4*q) = o;
        }
    }
}

// ---------------------------------------------------------------------------
// Scorer: 64 candidates/block, 256 threads = 8 row-groups x 32 col-threads,
// each thread 8 rows x 8 cols. Grid = 2048, 2 blocks/CU (8 waves).
// Per k: 2 ds_read_b128 + 2 global dwordx4 + 64 FMA.
// ---------------------------------------------------------------------------
__global__ __launch_bounds__(256, 2) void score_kernel(
    const float* __restrict__ s0, const float* __restrict__ eps,
    const float* __restrict__ mu_w1,
    const float* __restrict__ mu_w2, const float* __restrict__ mu_b2,
    const float* __restrict__ mu_w3, const float* __restrict__ mu_b3,
    const float* __restrict__ sig_w1, const float* __restrict__ sig_b1,
    const float* __restrict__ sig_w2, const float* __restrict__ sig_b2,
    const float* __restrict__ sig_w3, const float* __restrict__ sig_b3,
    const float* __restrict__ risk_w1,
    const float* __restrict__ risk_w2, const float* __restrict__ risk_b2,
    const float* __restrict__ risk_w3, const float* __restrict__ risk_b3,
    const float* __restrict__ base_mu, const float* __restrict__ base_risk,
    const float* __restrict__ mu, const float* __restrict__ stdv,
    float* __restrict__ score, int iter)
{
    __shared__ __align__(16) float zT[ZD_ * STRH_];   // z rows [d][r], r=0..63
    __shared__ __align__(16) float h[HID_ * STRH_];   // activations [c][r]
    __shared__ float w3m[2 * HID_];                   // mu_w3 cols 126/127 by k
    __shared__ float rw3[HID_];                       // risk_w3
    __shared__ float red[4][RT_], red2[4][RT_];       // 4-segment partials
    __shared__ float intentL[RT_], agencyL[RT_];
    __shared__ float muS[ZD_], stdS[ZD_];

    const int tid  = threadIdx.x;
    const int g    = tid >> 5;          // row-group 0..7: rows g*8..g*8+7
    const int g8   = g * 8;
    const int ct   = tid & 31;          // col-thread
    const int c0   = ct * 8;            // 8 cols owned in C=8 GEMMs
    const int row0 = blockIdx.x * RT_;  // 64 | 512 -> block shares one b
    const int b    = row0 >> 9;

    if (tid < ZD_) { muS[tid] = mu[b * ZD_ + tid]; stdS[tid] = stdv[b * ZD_ + tid]; }
    {   // stage w3 columns into LDS
        const float2 v = *(const float2*)(mu_w3 + (size_t)tid * 128 + 126);
        w3m[2 * tid] = v.x; w3m[2 * tid + 1] = v.y;
        rw3[tid] = risk_w3[tid];
    }
    __syncthreads();
    {   // z = mu + std*eps
        const float* epsI = eps + ((size_t)iter * B_ * S_ + row0) * ZD_;
        for (int l = tid; l < RT_ * ZD_; l += 256) {
            const int r = l >> 4, d = l & 15;
            zT[d * STRH_ + r] = fmaf(stdS[d], epsI[l], muS[d]);
        }
    }
    __syncthreads();

    float acc[8][8];

    // ---- mu chain -------------------------------------------------------
    {   // l1: K=16 z-part, init from base_mu (pre-activation)
        const float4 b0 = *(const float4*)(base_mu + (size_t)b * 256 + c0);
        const float4 b1v = *(const float4*)(base_mu + (size_t)b * 256 + c0 + 4);
        const float bb[8] = {b0.x,b0.y,b0.z,b0.w, b1v.x,b1v.y,b1v.z,b1v.w};
#pragma unroll
        for (int c = 0; c < 8; ++c)
#pragma unroll
            for (int r = 0; r < 8; ++r) acc[c][r] = bb[c];
        gemm_k8(zT + g8, ZD_, mu_w1 + (size_t)OBS_ * 256 + c0, acc);
        store8x8_relu(h, c0, g8, acc);
    }
    __syncthreads();
    {   // l2: K=256
        const float4 b0 = *(const float4*)(mu_b2 + c0);
        const float4 b1v = *(const float4*)(mu_b2 + c0 + 4);
        const float bb[8] = {b0.x,b0.y,b0.z,b0.w, b1v.x,b1v.y,b1v.z,b1v.w};
#pragma unroll
        for (int c = 0; c < 8; ++c)
#pragma unroll
            for (int r = 0; r < 8; ++r) acc[c][r] = bb[c];
        gemm_k8(h + g8, HID_, mu_w2 + c0, acc);
    }
    __syncthreads();
    store8x8_relu(h, c0, g8, acc);
    __syncthreads();
    {   // intent partials: 4 segs x 64 k, thread = (seg=tid>>6, r=tid&63)
        const int r = tid & 63, seg = tid >> 6;
        float p0 = 0.f, p1 = 0.f;
        for (int i = 0; i < 64; ++i) {
            const int k = seg * 64 + i;
            const float hv = h[k * STRH_ + r];
            p0 = fmaf(hv, w3m[2 * k],     p0);
            p1 = fmaf(hv, w3m[2 * k + 1], p1);
        }
        red[seg][r] = p0; red2[seg][r] = p1;
    }
    // ---- sig l1 compute (zT only; stores after barrier) -----------------
    {
        const float4 b0 = *(const float4*)(sig_b1 + c0);
        const float4 b1v = *(const float4*)(sig_b1 + c0 + 4);
        const float bb[8] = {b0.x,b0.y,b0.z,b0.w, b1v.x,b1v.y,b1v.z,b1v.w};
#pragma unroll
        for (int c = 0; c < 8; ++c)
#pragma unroll
            for (int r = 0; r < 8; ++r) acc[c][r] = bb[c];
        gemm_k8(zT + g8, ZD_, sig_w1 + c0, acc);
    }
    __syncthreads();
    store8x8_relu(h, c0, g8, acc);
    if (tid < RT_) {   // intent finalize
        float m0 = red[0][tid] + red[1][tid] + red[2][tid] + red[3][tid] + mu_b3[126];
        float m1 = red2[0][tid] + red2[1][tid] + red2[2][tid] + red2[3][tid] + mu_b3[127];
        const float g0 = s0[b * OBS_ + 2], g1 = s0[b * OBS_ + 3];
        const float d0 = m0 - g0, d1 = m1 - g1;
        intentL[tid] = d0 * d0 + d1 * d1;
    }
    __syncthreads();
    {   // sig l2: K=256
        const float4 b0 = *(const float4*)(sig_b2 + c0);
        const float4 b1v = *(const float4*)(sig_b2 + c0 + 4);
        const float bb[8] = {b0.x,b0.y,b0.z,b0.w, b1v.x,b1v.y,b1v.z,b1v.w};
#pragma unroll
        for (int c = 0; c < 8; ++c)
#pragma unroll
            for (int r = 0; r < 8; ++r) acc[c][r] = bb[c];
        gemm_k8(h + g8, HID_, sig_w2 + c0, acc);
    }
    __syncthreads();
    store8x8_relu(h, c0, g8, acc);
    __syncthreads();
    {   // sig l3: 128 cols (4/thread), K=256; clip; store rows of h[0..127]
        const int c3 = ct * 4;
        float a3[4][8];
        const float4 bv = *(const float4*)(sig_b3 + c3);
        const float bb[4] = {bv.x, bv.y, bv.z, bv.w};
#pragma unroll
        for (int c = 0; c < 4; ++c)
#pragma unroll
            for (int r = 0; r < 8; ++r) a3[c][r] = bb[c];
        gemm_l3(h + g8, HID_, sig_w3 + c3, a3);
        __syncthreads();   // all reads of h complete
#pragma unroll
        for (int c = 0; c < 4; ++c) {
#pragma unroll
            for (int q = 0; q < 2; ++q) {
                float4 o;
                o.x = fminf(fmaxf(a3[c][4*q+0], -4.f), 3.f);
                o.y = fminf(fmaxf(a3[c][4*q+1], -4.f), 3.f);
                o.z = fminf(fmaxf(a3[c][4*q+2], -4.f), 3.f);
                o.w = fminf(fmaxf(a3[c][4*q+3], -4.f), 3.f);
                *(float4*)(h + (size_t)(c3 + c) * STRH_ + g8 + 4*q) = o;
            }
        }
    }
    __syncthreads();
    {   // agency partials over 128 cols: 4 segs x 32 cols
        const int r = tid & 63, seg = tid >> 6;
        float s = 0.f;
        for (int i = 0; i < 32; ++i) s += h[(seg * 32 + i) * STRH_ + r];
        red[seg][r] = s;
    }
    // ---- risk l1 compute (base_risk + zT) -------------------------------
    {
        const float4 b0 = *(const float4*)(base_risk + (size_t)b * 256 + c0);
        const float4 b1v = *(const float4*)(base_risk + (size_t)b * 256 + c0 + 4);
        const float bb[8] = {b0.x,b0.y,b0.z,b0.w, b1v.x,b1v.y,b1v.z,b1v.w};
#pragma unroll
        for (int c = 0; c < 8; ++c)
#pragma unroll
            for (int r = 0; r < 8; ++r) acc[c][r] = bb[c];
        gemm_k8(zT + g8, ZD_, risk_w1 + (size_t)OBS_ * 256 + c0, acc);
    }
    __syncthreads();   // agency h-reads complete
    store8x8_relu(h, c0, g8, acc);
    if (tid < RT_) {   // agency finalize
        const float s = red[0][tid] + red[1][tid] + red[2][tid] + red[3][tid];
        agencyL[tid] = -s * (1.f / 128.f);
    }
    __syncthreads();
    {   // risk l2: K=256
        const float4 b0 = *(const float4*)(risk_b2 + c0);
        const float4 b1v = *(const float4*)(risk_b2 + c0 + 4);
        const float bb[8] = {b0.x,b0.y,b0.z,b0.w, b1v.x,b1v.y,b1v.z,b1v.w};
#pragma unroll
        for (int c = 0; c < 8; ++c)
#pragma unroll
            for (int r = 0; r < 8; ++r) acc[c][r] = bb[c];
        gemm_k8(h + g8, HID_, risk_w2 + c0, acc);
    }
    __syncthreads();
    store8x8_relu(h, c0, g8, acc);
    __syncthreads();
    {   // risk partials: 4 segs x 64 k (rw3 from LDS)
        const int r = tid & 63, seg = tid >> 6;
        float p = 0.f;
        for (int i = 0; i < 64; ++i) {
            const int k = seg * 64 + i;
            p = fmaf(h[k * STRH_ + r], rw3[k], p);
        }
        red[seg][r] = p;
    }
    __syncthreads();
    if (tid < RT_) {
        const float p = red[0][tid] + red[1][tid] + red[2][tid] + red[3][tid];
        const float risk = 1.f / (1.f + expf(-(p + risk_b3[0])));
        score[row0 + tid] = -intentL[tid] + 0.5f * agencyL[tid] - risk;
    }
}

// ---------------------------------------------------------------------------
// Per-batch-row CEM update (unchanged; verified bit-exact)
// ---------------------------------------------------------------------------
__global__ __launch_bounds__(256) void update_kernel(
    const float* __restrict__ score, const float* __restrict__ eps,
    float* __restrict__ mu, float* __restrict__ stdv,
    float* __restrict__ bscore, float* __restrict__ bz, int iter)
{
    __shared__ unsigned long long keys[512];
    __shared__ float ez[64][ZD_];
    __shared__ float mold[ZD_], sold[ZD_];
    __shared__ int flagL, idx0L;

    const int b = blockIdx.x, tid = threadIdx.x;

    for (int l = tid; l < 512; l += 256) {
        const float sc = score[b * 512 + l];
        unsigned int u = __float_as_uint(sc);
        u = (u & 0x80000000u) ? ~u : (u | 0x80000000u);
        const unsigned long long key =
            ((unsigned long long)u << 32) | (unsigned long long)(511 - l);
        keys[l] = ~key;
    }
    if (tid < ZD_) { mold[tid] = mu[b * ZD_ + tid]; sold[tid] = stdv[b * ZD_ + tid]; }
    __syncthreads();

    for (int size = 2; size < 512; size <<= 1) {
        const int ddd = ((tid & (size >> 1)) != 0) ? 0 : 1;
        for (int stride = size >> 1; stride > 0; stride >>= 1) {
            __syncthreads();
            const int pos = 2 * tid - (tid & (stride - 1));
            const unsigned long long a = keys[pos], c = keys[pos + stride];
            if ((a > c) == (ddd != 0)) { keys[pos] = c; keys[pos + stride] = a; }
        }
    }
    for (int stride = 256; stride > 0; stride >>= 1) {
        __syncthreads();
        const int pos = 2 * tid - (tid & (stride - 1));
        const unsigned long long a = keys[pos], c = keys[pos + stride];
        if (a > c) { keys[pos] = c; keys[pos + stride] = a; }
    }
    __syncthreads();

    const float* epsB = eps + ((size_t)iter * B_ * S_ + (size_t)b * S_) * ZD_;
    for (int l = tid; l < 64 * ZD_; l += 256) {
        const int e = l >> 4, d = l & 15;
        const unsigned long long key = ~keys[e];
        const int idx = 511 - (int)(key & 0xFFFFFFFFull);
        ez[e][d] = fmaf(sold[d], epsB[idx * ZD_ + d], mold[d]);
    }
    __syncthreads();

    if (tid < ZD_) {
        float s = 0.f;
        for (int e = 0; e < 64; ++e) s += ez[e][tid];
        const float mean = s * (1.f / 64.f);
        float v = 0.f;
        for (int e = 0; e < 64; ++e) { const float d = ez[e][tid] - mean; v = fmaf(d, d, v); }
        const float sd = sqrtf(v * (1.f / 63.f));
        mu[b * ZD_ + tid]   = 0.25f * mold[tid] + 0.75f * mean;
        stdv[b * ZD_ + tid] = fmaxf(0.25f * sold[tid] + 0.75f * sd, 0.2f);
    }
    if (tid == 0) {
        const unsigned long long key = ~keys[0];
        const int idx0 = 511 - (int)(key & 0xFFFFFFFFull);
        const float v = score[b * 512 + idx0];
        const int better = (v > bscore[b]) ? 1 : 0;
        if (better) bscore[b] = v;
        flagL = better; idx0L = idx0;
    }
    __syncthreads();
    if (tid < ZD_ && flagL)
        bz[b * ZD_ + tid] = fmaf(sold[tid], epsB[idx0L * ZD_ + tid], mold[tid]);
}

__global__ __launch_bounds__(256) void out_kernel(
    const float* __restrict__ bz, const float* __restrict__ bscore,
    float* __restrict__ out)
{
    const int i = blockIdx.x * 256 + threadIdx.x;
    if (i < B_ * 17) {
        const int b = i / 17, d = i % 17;
        out[i] = (d < ZD_) ? bz[b * ZD_ + d] : bscore[b];
    }
}

extern "C" void kernel_launch(void* const* d_in, const int* in_sizes, int n_in,
                              void* d_out, int out_size, void* d_ws, size_t ws_size,
                              hipStream_t stream)
{
    (void)in_sizes; (void)n_in; (void)out_size; (void)ws_size;
    const float* s0      = (const float*)d_in[0];
    const float* eps     = (const float*)d_in[1];
    const float* enc_w1  = (const float*)d_in[2];
    const float* enc_b1  = (const float*)d_in[3];
    const float* enc_w2  = (const float*)d_in[4];
    const float* enc_b2  = (const float*)d_in[5];
    const float* zmu_w   = (const float*)d_in[6];
    const float* zmu_b   = (const float*)d_in[7];
    const float* zls_w   = (const float*)d_in[8];
    const float* zls_b   = (const float*)d_in[9];
    const float* mu_w1   = (const float*)d_in[10];
    const float* mu_b1   = (const float*)d_in[11];
    const float* mu_w2   = (const float*)d_in[12];
    const float* mu_b2   = (const float*)d_in[13];
    const float* mu_w3   = (const float*)d_in[14];
    const float* mu_b3   = (const float*)d_in[15];
    const float* sig_w1  = (const float*)d_in[16];
    const float* sig_b1  = (const float*)d_in[17];
    const float* sig_w2  = (const float*)d_in[18];
    const float* sig_b2  = (const float*)d_in[19];
    const float* sig_w3  = (const float*)d_in[20];
    const float* sig_b3  = (const float*)d_in[21];
    const float* risk_w1 = (const float*)d_in[22];
    const float* risk_b1 = (const float*)d_in[23];
    const float* risk_w2 = (const float*)d_in[24];
    const float* risk_b2 = (const float*)d_in[25];
    const float* risk_w3 = (const float*)d_in[26];
    const float* risk_b3 = (const float*)d_in[27];

    float* ws        = (float*)d_ws;
    float* mu        = ws;                  // 4096
    float* stdv      = ws + 4096;           // 4096
    float* bscore    = ws + 8192;           // 256
    float* bz        = ws + 8448;           // 4096
    float* score     = ws + 12544;          // 131072
    float* base_mu   = ws + 143616;         // 65536
    float* base_risk = ws + 209152;         // 65536

    enc_kernel<<<B_, 256, 0, stream>>>(s0, enc_w1, enc_b1, enc_w2, enc_b2,
                                       zmu_w, zmu_b, zls_w, zls_b,
                                       mu_w1, mu_b1, risk_w1, risk_b1,
                                       mu, stdv, bscore, base_mu, base_risk);
    for (int it = 0; it < ITERS_; ++it) {
        score_kernel<<<(B_ * S_) / RT_, 256, 0, stream>>>(
            s0, eps,
            mu_w1, mu_w2, mu_b2, mu_w3, mu_b3,
            sig_w1, sig_b1, sig_w2, sig_b2, sig_w3, sig_b3,
            risk_w1, risk_w2, risk_b2, risk_w3, risk_b3,
            base_mu, base_risk,
            mu, stdv, score, it);
        update_kernel<<<B_, 256, 0, stream>>>(score, eps, mu, stdv, bscore, bz, it);
    }
    out_kernel<<<(B_ * 17 + 255) / 256, 256, 0, stream>>>(bz, bscore,
                                                          (float*)d_out);
}

// Round 13
// 2883.486 us; speedup vs baseline: 1.0773x; 1.0773x over previous
//
#include <hip/hip_runtime.h>

#define B_    256
#define S_    512
#define OBS_  64
#define ZD_   16
#define HID_  256
#define ITERS_ 4
#define RT_   64          // candidates (rows) per block (four 16-row groups)
#define STRH_ 68          // LDS leading stride: 64 rows + 4 pad

// ---------------------------------------------------------------------------
// Encoder + per-batch-row layer-1 s0-part precompute (pre-activation):
//   base_mu[b][c]   = s0[b]@mu_w1[:64,c]   + mu_b1[c]
//   base_risk[b][c] = s0[b]@risk_w1[:64,c] + risk_b1[c]
// ---------------------------------------------------------------------------
__global__ __launch_bounds__(256) void enc_kernel(
    const float* __restrict__ s0,
    const float* __restrict__ w1, const float* __restrict__ b1,
    const float* __restrict__ w2, const float* __restrict__ b2,
    const float* __restrict__ zmw, const float* __restrict__ zmb,
    const float* __restrict__ zlw, const float* __restrict__ zlb,
    const float* __restrict__ mu_w1, const float* __restrict__ mu_b1,
    const float* __restrict__ risk_w1, const float* __restrict__ risk_b1,
    float* __restrict__ mu, float* __restrict__ stdv, float* __restrict__ bscore,
    float* __restrict__ base_mu, float* __restrict__ base_risk)
{
    __shared__ float s0s[OBS_];
    __shared__ float h1[HID_];
    __shared__ float h2[HID_];
    const int b = blockIdx.x, tid = threadIdx.x;
    if (tid < OBS_) s0s[tid] = s0[b * OBS_ + tid];
    __syncthreads();
    {
        float am = mu_b1[tid], ar = risk_b1[tid];
        for (int k = 0; k < OBS_; ++k) {
            am = fmaf(s0s[k], mu_w1[k * 256 + tid], am);
            ar = fmaf(s0s[k], risk_w1[k * 256 + tid], ar);
        }
        base_mu[b * 256 + tid]   = am;
        base_risk[b * 256 + tid] = ar;
    }
    float a = b1[tid];
    for (int k = 0; k < OBS_; ++k) a = fmaf(s0s[k], w1[k * HID_ + tid], a);
    h1[tid] = fmaxf(a, 0.f);
    __syncthreads();
    float a2 = b2[tid];
    for (int k = 0; k < HID_; ++k) a2 = fmaf(h1[k], w2[k * HID_ + tid], a2);
    h2[tid] = fmaxf(a2, 0.f);
    __syncthreads();
    if (tid < ZD_) {
        float m = zmb[tid];
        for (int k = 0; k < HID_; ++k) m = fmaf(h2[k], zmw[k * ZD_ + tid], m);
        mu[b * ZD_ + tid] = m;
    } else if (tid < 2 * ZD_) {
        const int d = tid - ZD_;
        float l = zlb[d];
        for (int k = 0; k < HID_; ++k) l = fmaf(h2[k], zlw[k * ZD_ + d], l);
        l = fminf(fmaxf(l, -4.f), 2.f);
        stdv[b * ZD_ + d] = expf(l);
    } else if (tid == 2 * ZD_) {
        bscore[b] = -INFINITY;
    }
}

// 16 rows x 4 cols of FMAs from one broadcast LDS row segment (4 b128 reads)
__device__ __forceinline__ void fma16x4(
    const float* __restrict__ row, float4 w,
    float* __restrict__ a0, float* __restrict__ a1,
    float* __restrict__ a2, float* __restrict__ a3)
{
    const float4 q0 = *(const float4*)(row);
    const float4 q1 = *(const float4*)(row + 4);
    const float4 q2 = *(const float4*)(row + 8);
    const float4 q3 = *(const float4*)(row + 12);
    const float aa[16] = {q0.x,q0.y,q0.z,q0.w, q1.x,q1.y,q1.z,q1.w,
                          q2.x,q2.y,q2.z,q2.w, q3.x,q3.y,q3.z,q3.w};
#pragma unroll
    for (int r = 0; r < 16; ++r) {
        a0[r] = fmaf(aa[r], w.x, a0[r]);
        a1[r] = fmaf(aa[r], w.y, a1[r]);
        a2[r] = fmaf(aa[r], w.z, a2[r]);
        a3[r] = fmaf(aa[r], w.w, a3[r]);
    }
}

// 16 rows x 2 cols (for sig l3)
__device__ __forceinline__ void fma16x2(
    const float* __restrict__ row, float wx, float wy,
    float* __restrict__ a0, float* __restrict__ a1)
{
    const float4 q0 = *(const float4*)(row);
    const float4 q1 = *(const float4*)(row + 4);
    const float4 q2 = *(const float4*)(row + 8);
    const float4 q3 = *(const float4*)(row + 12);
    const float aa[16] = {q0.x,q0.y,q0.z,q0.w, q1.x,q1.y,q1.z,q1.w,
                          q2.x,q2.y,q2.z,q2.w, q3.x,q3.y,q3.z,q3.w};
#pragma unroll
    for (int r = 0; r < 16; ++r) {
        a0[r] = fmaf(aa[r], wx, a0[r]);
        a1[r] = fmaf(aa[r], wy, a1[r]);
    }
}

// 4-col GEMM over 16 rows; K multiple of 8; 4+4 float4 weight prefetch.
// inS points at this row-group's 16-float segment; wcol = W + c0 (stride 256).
__device__ __forceinline__ void gemm_k4(
    const float* __restrict__ inS, int K,
    const float* __restrict__ wcol,
    float* __restrict__ a0, float* __restrict__ a1,
    float* __restrict__ a2, float* __restrict__ a3)
{
    float4 wA[4], wB[4];
#pragma unroll
    for (int i = 0; i < 4; ++i) wA[i] = *(const float4*)(wcol + (size_t)i * 256);
#pragma unroll 1
    for (int k0 = 0; k0 < K; k0 += 8) {
#pragma unroll
        for (int i = 0; i < 4; ++i)
            wB[i] = *(const float4*)(wcol + (size_t)(k0 + 4 + i) * 256);
#pragma unroll
        for (int i = 0; i < 4; ++i)
            fma16x4(inS + (k0 + i) * STRH_, wA[i], a0, a1, a2, a3);
        if (k0 + 8 < K) {
#pragma unroll
            for (int i = 0; i < 4; ++i)
                wA[i] = *(const float4*)(wcol + (size_t)(k0 + 8 + i) * 256);
        }
#pragma unroll
        for (int i = 0; i < 4; ++i)
            fma16x4(inS + (k0 + 4 + i) * STRH_, wB[i], a0, a1, a2, a3);
    }
}

// 2-col GEMM over 16 rows (sig l3: stride 128, float2 weights)
__device__ __forceinline__ void gemm_l3(
    const float* __restrict__ inS, int K,
    const float* __restrict__ wcol,
    float* __restrict__ a0, float* __restrict__ a1)
{
    float2 wA[4], wB[4];
#pragma unroll
    for (int i = 0; i < 4; ++i) wA[i] = *(const float2*)(wcol + (size_t)i * 128);
#pragma unroll 1
    for (int k0 = 0; k0 < K; k0 += 8) {
#pragma unroll
        for (int i = 0; i < 4; ++i)
            wB[i] = *(const float2*)(wcol + (size_t)(k0 + 4 + i) * 128);
#pragma unroll
        for (int i = 0; i < 4; ++i)
            fma16x2(inS + (k0 + i) * STRH_, wA[i].x, wA[i].y, a0, a1);
        if (k0 + 8 < K) {
#pragma unroll
            for (int i = 0; i < 4; ++i)
                wA[i] = *(const float2*)(wcol + (size_t)(k0 + 8 + i) * 128);
        }
#pragma unroll
        for (int i = 0; i < 4; ++i)
            fma16x2(inS + (k0 + 4 + i) * STRH_, wB[i].x, wB[i].y, a0, a1);
    }
}

__device__ __forceinline__ void store16_relu(float* __restrict__ dst, int c,
                                             int g16, const float* __restrict__ acc)
{
#pragma unroll
    for (int q = 0; q < 4; ++q) {
        float4 o;
        o.x = fmaxf(acc[4*q+0], 0.f); o.y = fmaxf(acc[4*q+1], 0.f);
        o.z = fmaxf(acc[4*q+2], 0.f); o.w = fmaxf(acc[4*q+3], 0.f);
        *(float4*)(dst + (size_t)c * STRH_ + g16 + 4*q) = o;
    }
}

// ---------------------------------------------------------------------------
// Scorer: 64 candidates/block, 256 threads = 4 row-groups x 64 col-threads,
// each thread 16 rows x 4 cols. Grid = B*S/64 = 2048. LDS ~79.7 KB ->
// 2 blocks/CU (8 waves). Per k: 4 ds_read_b128 + 1 dwordx4 + 64 FMA.
// ---------------------------------------------------------------------------
__global__ __launch_bounds__(256, 2) void score_kernel(
    const float* __restrict__ s0, const float* __restrict__ eps,
    const float* __restrict__ mu_w1,
    const float* __restrict__ mu_w2, const float* __restrict__ mu_b2,
    const float* __restrict__ mu_w3, const float* __restrict__ mu_b3,
    const float* __restrict__ sig_w1, const float* __restrict__ sig_b1,
    const float* __restrict__ sig_w2, const float* __restrict__ sig_b2,
    const float* __restrict__ sig_w3, const float* __restrict__ sig_b3,
    const float* __restrict__ risk_w1,
    const float* __restrict__ risk_w2, const float* __restrict__ risk_b2,
    const float* __restrict__ risk_w3, const float* __restrict__ risk_b3,
    const float* __restrict__ base_mu, const float* __restrict__ base_risk,
    const float* __restrict__ mu, const float* __restrict__ stdv,
    float* __restrict__ score, int iter)
{
    __shared__ __align__(16) float zT[ZD_ * STRH_];   // z rows [d][r], r=0..63
    __shared__ __align__(16) float h[HID_ * STRH_];   // activations [c][r]
    __shared__ float w3m[2 * HID_];                   // mu_w3 cols 126/127 by k
    __shared__ float rw3[HID_];                       // risk_w3
    __shared__ float red[4][RT_], red2[4][RT_];       // 4-segment partials
    __shared__ float intentL[RT_], agencyL[RT_];
    __shared__ float muS[ZD_], stdS[ZD_];

    const int tid  = threadIdx.x;
    const int g    = tid >> 6;          // row-group 0..3: rows g*16..g*16+15
    const int g16  = g * 16;
    const int ct   = tid & 63;          // col-thread
    const int c0   = ct * 4;            // 4 cols owned in C=4 GEMMs
    const int row0 = blockIdx.x * RT_;  // 64 | 512 -> block shares one b
    const int b    = row0 >> 9;

    if (tid < ZD_) { muS[tid] = mu[b * ZD_ + tid]; stdS[tid] = stdv[b * ZD_ + tid]; }
    {   // stage w3 columns into LDS (removes global loads from reduce loops)
        const float2 v = *(const float2*)(mu_w3 + (size_t)tid * 128 + 126);
        w3m[2 * tid] = v.x; w3m[2 * tid + 1] = v.y;
        rw3[tid] = risk_w3[tid];
    }
    __syncthreads();
    {   // z = mu + std*eps
        const float* epsI = eps + ((size_t)iter * B_ * S_ + row0) * ZD_;
        for (int l = tid; l < RT_ * ZD_; l += 256) {
            const int r = l >> 4, d = l & 15;
            zT[d * STRH_ + r] = fmaf(stdS[d], epsI[l], muS[d]);
        }
    }
    __syncthreads();

    float a0[16], a1[16], a2[16], a3[16];

    // ---- mu chain -------------------------------------------------------
    {   // l1: K=16 z-part, init from base_mu (pre-activation)
        const float4 bm = *(const float4*)(base_mu + (size_t)b * 256 + c0);
#pragma unroll
        for (int r = 0; r < 16; ++r) { a0[r] = bm.x; a1[r] = bm.y; a2[r] = bm.z; a3[r] = bm.w; }
        gemm_k4(zT + g16, ZD_, mu_w1 + (size_t)OBS_ * 256 + c0, a0, a1, a2, a3);
        store16_relu(h, c0, g16, a0); store16_relu(h, c0 + 1, g16, a1);
        store16_relu(h, c0 + 2, g16, a2); store16_relu(h, c0 + 3, g16, a3);
    }
    __syncthreads();
    {   // l2: K=256
        const float4 bv = *(const float4*)(mu_b2 + c0);
#pragma unroll
        for (int r = 0; r < 16; ++r) { a0[r] = bv.x; a1[r] = bv.y; a2[r] = bv.z; a3[r] = bv.w; }
        gemm_k4(h + g16, HID_, mu_w2 + c0, a0, a1, a2, a3);
    }
    __syncthreads();
    store16_relu(h, c0, g16, a0); store16_relu(h, c0 + 1, g16, a1);
    store16_relu(h, c0 + 2, g16, a2); store16_relu(h, c0 + 3, g16, a3);
    __syncthreads();
    {   // intent partials: 4 segs x 64 k, thread = (seg=tid>>6, r=tid&63)
        const int r = tid & 63, seg = tid >> 6;
        float p0 = 0.f, p1 = 0.f;
        for (int i = 0; i < 64; ++i) {
            const int k = seg * 64 + i;
            const float hv = h[k * STRH_ + r];
            p0 = fmaf(hv, w3m[2 * k],     p0);
            p1 = fmaf(hv, w3m[2 * k + 1], p1);
        }
        red[seg][r] = p0; red2[seg][r] = p1;
    }
    // ---- sig l1 compute (zT only; stores after barrier) -----------------
    {
        const float4 bv = *(const float4*)(sig_b1 + c0);
#pragma unroll
        for (int r = 0; r < 16; ++r) { a0[r] = bv.x; a1[r] = bv.y; a2[r] = bv.z; a3[r] = bv.w; }
        gemm_k4(zT + g16, ZD_, sig_w1 + c0, a0, a1, a2, a3);
    }
    __syncthreads();
    store16_relu(h, c0, g16, a0); store16_relu(h, c0 + 1, g16, a1);
    store16_relu(h, c0 + 2, g16, a2); store16_relu(h, c0 + 3, g16, a3);
    if (tid < RT_) {   // intent finalize
        float m0 = red[0][tid] + red[1][tid] + red[2][tid] + red[3][tid] + mu_b3[126];
        float m1 = red2[0][tid] + red2[1][tid] + red2[2][tid] + red2[3][tid] + mu_b3[127];
        const float g0 = s0[b * OBS_ + 2], g1 = s0[b * OBS_ + 3];
        const float d0 = m0 - g0, d1 = m1 - g1;
        intentL[tid] = d0 * d0 + d1 * d1;
    }
    __syncthreads();
    {   // sig l2: K=256
        const float4 bv = *(const float4*)(sig_b2 + c0);
#pragma unroll
        for (int r = 0; r < 16; ++r) { a0[r] = bv.x; a1[r] = bv.y; a2[r] = bv.z; a3[r] = bv.w; }
        gemm_k4(h + g16, HID_, sig_w2 + c0, a0, a1, a2, a3);
    }
    __syncthreads();
    store16_relu(h, c0, g16, a0); store16_relu(h, c0 + 1, g16, a1);
    store16_relu(h, c0 + 2, g16, a2); store16_relu(h, c0 + 3, g16, a3);
    __syncthreads();
    {   // sig l3: 128 cols (2/thread), K=256; clip; store rows of h[0..127]
        const int c2 = ct * 2;
        float s0a[16], s1a[16];
        const float2 bv = *(const float2*)(sig_b3 + c2);
#pragma unroll
        for (int r = 0; r < 16; ++r) { s0a[r] = bv.x; s1a[r] = bv.y; }
        gemm_l3(h + g16, HID_, sig_w3 + c2, s0a, s1a);
        __syncthreads();   // all reads of h complete
#pragma unroll
        for (int q = 0; q < 4; ++q) {
            float4 o;
            o.x = fminf(fmaxf(s0a[4*q+0], -4.f), 3.f);
            o.y = fminf(fmaxf(s0a[4*q+1], -4.f), 3.f);
            o.z = fminf(fmaxf(s0a[4*q+2], -4.f), 3.f);
            o.w = fminf(fmaxf(s0a[4*q+3], -4.f), 3.f);
            *(float4*)(h + (size_t)c2 * STRH_ + g16 + 4*q) = o;
        }
#pragma unroll
        for (int q = 0; q < 4; ++q) {
            float4 o;
            o.x = fminf(fmaxf(s1a[4*q+0], -4.f), 3.f);
            o.y = fminf(fmaxf(s1a[4*q+1], -4.f), 3.f);
            o.z = fminf(fmaxf(s1a[4*q+2], -4.f), 3.f);
            o.w = fminf(fmaxf(s1a[4*q+3], -4.f), 3.f);
            *(float4*)(h + (size_t)(c2 + 1) * STRH_ + g16 + 4*q) = o;
        }
    }
    __syncthreads();
    {   // agency partials over 128 cols: 4 segs x 32 cols
        const int r = tid & 63, seg = tid >> 6;
        float s = 0.f;
        for (int i = 0; i < 32; ++i) s += h[(seg * 32 + i) * STRH_ + r];
        red[seg][r] = s;
    }
    // ---- risk l1 compute (base_risk + zT) -------------------------------
    {
        const float4 bm = *(const float4*)(base_risk + (size_t)b * 256 + c0);
#pragma unroll
        for (int r = 0; r < 16; ++r) { a0[r] = bm.x; a1[r] = bm.y; a2[r] = bm.z; a3[r] = bm.w; }
        gemm_k4(zT + g16, ZD_, risk_w1 + (size_t)OBS_ * 256 + c0, a0, a1, a2, a3);
    }
    __syncthreads();   // agency h-reads complete
    store16_relu(h, c0, g16, a0); store16_relu(h, c0 + 1, g16, a1);
    store16_relu(h, c0 + 2, g16, a2); store16_relu(h, c0 + 3, g16, a3);
    if (tid < RT_) {   // agency finalize
        const float s = red[0][tid] + red[1][tid] + red[2][tid] + red[3][tid];
        agencyL[tid] = -s * (1.f / 128.f);
    }
    __syncthreads();
    {   // risk l2: K=256
        const float4 bv = *(const float4*)(risk_b2 + c0);
#pragma unroll
        for (int r = 0; r < 16; ++r) { a0[r] = bv.x; a1[r] = bv.y; a2[r] = bv.z; a3[r] = bv.w; }
        gemm_k4(h + g16, HID_, risk_w2 + c0, a0, a1, a2, a3);
    }
    __syncthreads();
    store16_relu(h, c0, g16, a0); store16_relu(h, c0 + 1, g16, a1);
    store16_relu(h, c0 + 2, g16, a2); store16_relu(h, c0 + 3, g16, a3);
    __syncthreads();
    {   // risk partials: 4 segs x 64 k (rw3 from LDS)
        const int r = tid & 63, seg = tid >> 6;
        float p = 0.f;
        for (int i = 0; i < 64; ++i) {
            const int k = seg * 64 + i;
            p = fmaf(h[k * STRH_ + r], rw3[k], p);
        }
        red[seg][r] = p;
    }
    __syncthreads();
    if (tid < RT_) {
        const float p = red[0][tid] + red[1][tid] + red[2][tid] + red[3][tid];
        const float risk = 1.f / (1.f + expf(-(p + risk_b3[0])));
        score[row0 + tid] = -intentL[tid] + 0.5f * agencyL[tid] - risk;
    }
}

// ---------------------------------------------------------------------------
// Per-batch-row CEM update (unchanged; verified bit-exact)
// ---------------------------------------------------------------------------
__global__ __launch_bounds__(256) void update_kernel(
    const float* __restrict__ score, const float* __restrict__ eps,
    float* __restrict__ mu, float* __restrict__ stdv,
    float* __restrict__ bscore, float* __restrict__ bz, int iter)
{
    __shared__ unsigned long long keys[512];
    __shared__ float ez[64][ZD_];
    __shared__ float mold[ZD_], sold[ZD_];
    __shared__ int flagL, idx0L;

    const int b = blockIdx.x, tid = threadIdx.x;

    for (int l = tid; l < 512; l += 256) {
        const float sc = score[b * 512 + l];
        unsigned int u = __float_as_uint(sc);
        u = (u & 0x80000000u) ? ~u : (u | 0x80000000u);
        const unsigned long long key =
            ((unsigned long long)u << 32) | (unsigned long long)(511 - l);
        keys[l] = ~key;
    }
    if (tid < ZD_) { mold[tid] = mu[b * ZD_ + tid]; sold[tid] = stdv[b * ZD_ + tid]; }
    __syncthreads();

    for (int size = 2; size < 512; size <<= 1) {
        const int ddd = ((tid & (size >> 1)) != 0) ? 0 : 1;
        for (int stride = size >> 1; stride > 0; stride >>= 1) {
            __syncthreads();
            const int pos = 2 * tid - (tid & (stride - 1));
            const unsigned long long a = keys[pos], c = keys[pos + stride];
            if ((a > c) == (ddd != 0)) { keys[pos] = c; keys[pos + stride] = a; }
        }
    }
    for (int stride = 256; stride > 0; stride >>= 1) {
        __syncthreads();
        const int pos = 2 * tid - (tid & (stride - 1));
        const unsigned long long a = keys[pos], c = keys[pos + stride];
        if (a > c) { keys[pos] = c; keys[pos + stride] = a; }
    }
    __syncthreads();

    const float* epsB = eps + ((size_t)iter * B_ * S_ + (size_t)b * S_) * ZD_;
    for (int l = tid; l < 64 * ZD_; l += 256) {
        const int e = l >> 4, d = l & 15;
        const unsigned long long key = ~keys[e];
        const int idx = 511 - (int)(key & 0xFFFFFFFFull);
        ez[e][d] = fmaf(sold[d], epsB[idx * ZD_ + d], mold[d]);
    }
    __syncthreads();

    if (tid < ZD_) {
        float s = 0.f;
        for (int e = 0; e < 64; ++e) s += ez[e][tid];
        const float mean = s * (1.f / 64.f);
        float v = 0.f;
        for (int e = 0; e < 64; ++e) { const float d = ez[e][tid] - mean; v = fmaf(d, d, v); }
        const float sd = sqrtf(v * (1.f / 63.f));
        mu[b * ZD_ + tid]   = 0.25f * mold[tid] + 0.75f * mean;
        stdv[b * ZD_ + tid] = fmaxf(0.25f * sold[tid] + 0.75f * sd, 0.2f);
    }
    if (tid == 0) {
        const unsigned long long key = ~keys[0];
        const int idx0 = 511 - (int)(key & 0xFFFFFFFFull);
        const float v = score[b * 512 + idx0];
        const int better = (v > bscore[b]) ? 1 : 0;
        if (better) bscore[b] = v;
        flagL = better; idx0L = idx0;
    }
    __syncthreads();
    if (tid < ZD_ && flagL)
        bz[b * ZD_ + tid] = fmaf(sold[tid], epsB[idx0L * ZD_ + tid], mold[tid]);
}

__global__ __launch_bounds__(256) void out_kernel(
    const float* __restrict__ bz, const float* __restrict__ bscore,
    float* __restrict__ out)
{
    const int i = blockIdx.x * 256 + threadIdx.x;
    if (i < B_ * 17) {
        const int b = i / 17, d = i % 17;
        out[i] = (d < ZD_) ? bz[b * ZD_ + d] : bscore[b];
    }
}

extern "C" void kernel_launch(void* const* d_in, const int* in_sizes, int n_in,
                              void* d_out, int out_size, void* d_ws, size_t ws_size,
                              hipStream_t stream)
{
    (void)in_sizes; (void)n_in; (void)out_size; (void)ws_size;
    const float* s0      = (const float*)d_in[0];
    const float* eps     = (const float*)d_in[1];
    const float* enc_w1  = (const float*)d_in[2];
    const float* enc_b1  = (const float*)d_in[3];
    const float* enc_w2  = (const float*)d_in[4];
    const float* enc_b2  = (const float*)d_in[5];
    const float* zmu_w   = (const float*)d_in[6];
    const float* zmu_b   = (const float*)d_in[7];
    const float* zls_w   = (const float*)d_in[8];
    const float* zls_b   = (const float*)d_in[9];
    const float* mu_w1   = (const float*)d_in[10];
    const float* mu_b1   = (const float*)d_in[11];
    const float* mu_w2   = (const float*)d_in[12];
    const float* mu_b2   = (const float*)d_in[13];
    const float* mu_w3   = (const float*)d_in[14];
    const float* mu_b3   = (const float*)d_in[15];
    const float* sig_w1  = (const float*)d_in[16];
    const float* sig_b1  = (const float*)d_in[17];
    const float* sig_w2  = (const float*)d_in[18];
    const float* sig_b2  = (const float*)d_in[19];
    const float* sig_w3  = (const float*)d_in[20];
    const float* sig_b3  = (const float*)d_in[21];
    const float* risk_w1 = (const float*)d_in[22];
    const float* risk_b1 = (const float*)d_in[23];
    const float* risk_w2 = (const float*)d_in[24];
    const float* risk_b2 = (const float*)d_in[25];
    const float* risk_w3 = (const float*)d_in[26];
    const float* risk_b3 = (const float*)d_in[27];

    float* ws        = (float*)d_ws;
    float* mu        = ws;                  // 4096
    float* stdv      = ws + 4096;           // 4096
    float* bscore    = ws + 8192;           // 256
    float* bz        = ws + 8448;           // 4096
    float* score     = ws + 12544;          // 131072
    float* base_mu   = ws + 143616;         // 65536
    float* base_risk = ws + 209152;         // 65536

    enc_kernel<<<B_, 256, 0, stream>>>(s0, enc_w1, enc_b1, enc_w2, enc_b2,
                                       zmu_w, zmu_b, zls_w, zls_b,
                                       mu_w1, mu_b1, risk_w1, risk_b1,
                                       mu, stdv, bscore, base_mu, base_risk);
    for (int it = 0; it < ITERS_; ++it) {
        score_kernel<<<(B_ * S_) / RT_, 256, 0, stream>>>(
            s0, eps,
            mu_w1, mu_w2, mu_b2, mu_w3, mu_b3,
            sig_w1, sig_b1, sig_w2, sig_b2, sig_w3, sig_b3,
            risk_w1, risk_w2, risk_b2, risk_w3, risk_b3,
            base_mu, base_risk,
            mu, stdv, score, it);
        update_kernel<<<B_, 256, 0, stream>>>(score, eps, mu, stdv, bscore, bz, it);
    }
    out_kernel<<<(B_ * 17 + 255) / 256, 256, 0, stream>>>(bz, bscore,
                                                          (float*)d_out);
}